// Round 16
// baseline (12175.713 us; speedup 1.0000x reference)
//
#include <hip/hip_runtime.h>

#define T_N 4096
#define B_N 64
#define D_N 128

typedef _Float16 f16;
typedef _Float16 f16x4 __attribute__((ext_vector_type(4)));
typedef _Float16 f16x8 __attribute__((ext_vector_type(8)));
typedef __fp16 fp16x2 __attribute__((ext_vector_type(2)));
typedef float f32x16 __attribute__((ext_vector_type(16)));
typedef unsigned int u32;
typedef unsigned int u32x2 __attribute__((ext_vector_type(2)));

__device__ __forceinline__ f16x8 cat8(f16x4 a, f16x4 b) {
  return __builtin_shufflevector(a, b, 0, 1, 2, 3, 4, 5, 6, 7);
}
__device__ __forceinline__ u32 pk2(f16 a, f16 b) {
  union { f16 x[2]; u32 u; } z;
  z.x[0] = a; z.x[1] = b;
  return z.u;
}
__device__ __forceinline__ u32 pkrtz(float a, float b) {
  union { fp16x2 h; u32 u; } z;
  z.h = __builtin_amdgcn_cvt_pkrtz(a, b);
  return z.u;
}
// own + partner-half value, branchless (HW-verified in R11):
// permlane32_swap(a,a) -> out0 = low-half value, out1 = high-half value for
// every lane, so out0+out1 = own + partner in both halves.
__device__ __forceinline__ float hsum32(float v) {
  union { float f; u32 u; } a; a.f = v;
  u32x2 r = __builtin_amdgcn_permlane32_swap(a.u, a.u, false, false);
  union { u32 u; float f; } o0, o1;
  o0.u = r[0]; o1.u = r[1];
  return o0.f + o1.f;
}

// raw barrier: LDS-visibility only; does NOT drain vmcnt (prefetch stays in flight)
__device__ __forceinline__ void wg_barrier() {
  asm volatile("s_waitcnt lgkmcnt(0)" ::: "memory");
  __builtin_amdgcn_sched_barrier(0);
  __builtin_amdgcn_s_barrier();
  __builtin_amdgcn_sched_barrier(0);
}

// B/A fragment builder (k-slot layout empirically verified end-to-end vs CPU
// reference across m1/m1'/m2 with random data, rounds 5-15).
__device__ __forceinline__ f16x8 bfrag(int h, u32 qs0, u32 qs1, u32 qt0, u32 qt1) {
  u32x2 s0 = __builtin_amdgcn_permlane32_swap(qs0, qt0, false, false);
  u32x2 s1 = __builtin_amdgcn_permlane32_swap(qs1, qt1, false, false);
  union { u32 u[4]; f16x8 v; } z;
  z.u[0] = s0[0]; z.u[1] = s1[0]; z.u[2] = s0[1]; z.u[3] = s1[1];
  return z.v;
}

// Sequential RLS scan, single-barrier pipeline (R15 champion structure):
// 8 waves. Waves 0-3 ("P") hold Pt = FF^t*P in MFMA accumulators; waves 4-7
// ("IO") stage x into a TRIPLE-buffered f16 LDS tile set during phase 1.
// ONE barrier per step (mid-step). Race audit unchanged from R11.
// ft-FREEZE (this round): km = -(ft/64)K packs below the smallest f16
// denormal (6e-8) once ft < 4e-6 (t >= ~1240). From then on the G MFMAs add
// exactly zero to Pacc -> skip kq pack + xt reads + G via wave-uniform
// branch. Theta's tsum path (f32, rescaled by 1/ft) is NOT small: kept.
__global__ __launch_bounds__(512, 1) void rls_seq(
    const float* __restrict__ xg, const float* __restrict__ tg,
    float* __restrict__ attn) {
  constexpr float FF = 0.99f, EPS = 1e-8f;
  constexpr float FEPS = FF + EPS;
  constexpr float INVB = 1.0f / 64.0f;
  constexpr float FCUT = 4e-6f;  // f16-denormal floor for km pack

  // u32-strides mod 4 == 2 -> 2-way (free) bank aliasing
  __shared__ alignas(16) f16 X16[3][64][132];    // x16[b][j]
  __shared__ alignas(16) f16 Xt16[3][128][68];   // x16[b][j] stored [j][b]
  __shared__ alignas(16) float theta[128];
  __shared__ alignas(16) float pairs[2][4][64][2];  // per-step-parity (q,y) partials
  __shared__ alignas(16) float rw[4][64][2];        // per-P-wave private (rdm, err)

  const int tid = threadIdx.x;
  const int wid = tid >> 6;       // 0..3 P-waves, 4..7 IO-waves
  const int lane = tid & 63;
  const int l31 = lane & 31;
  const int h = lane >> 5;
  const int w = wid & 3;          // P: owned i-tile. IO: staging column group.
  const int i32 = 32 * w + l31;   // P-wave: this lane's P row index i

  // Pacc tile jm, element r  <->  Pt[i32][j], j = 32*jm + (r&3) + 8*(r>>2) + 4*h
  f32x16 Pacc[4];
  if (wid < 4) {
#pragma unroll
    for (int jm = 0; jm < 4; ++jm)
#pragma unroll
      for (int r = 0; r < 16; ++r) {
        const int j = 32 * jm + (r & 3) + 8 * (r >> 2) + 4 * h;
        Pacc[jm][r] = (j == i32) ? 100.0f : 0.0f;  // P0 = I/lambda, ft0 = 1
      }
    if (tid < 128) theta[tid] = 0.0f;
  }

  // staging mapping (IO-waves): thread covers rows (2p,2p+1), cols 16*jbk..+15
  const int p = l31;
  const int jbk = 2 * w + h;
  const long rstride = (long)T_N * D_N;
  const float* xrow0 = xg + (long)(2 * p) * rstride + 16 * jbk;

  float4 xr[8];
  float tcur = 0.0f, tnxt = 0.0f;
  float ft = 1.0f;  // FF^t
  int pb = 0;       // t % 3

  f32x16 Z;  // persistent zero accumulator
#pragma unroll
  for (int r = 0; r < 16; ++r) Z[r] = 0.0f;

#define XLOAD(tt)                                                     \
  {                                                                   \
    _Pragma("unroll") for (int q = 0; q < 4; ++q) {                   \
      xr[q] = *(const float4*)(xrow0 + (long)(tt)*D_N + 4 * q);       \
      xr[4 + q] = *(const float4*)(xrow0 + rstride + (long)(tt)*D_N + 4 * q); \
    }                                                                 \
  }

#define XPREP(bidx)                                                   \
  {                                                                   \
    f16 c0[16], c1[16];                                               \
    _Pragma("unroll") for (int q = 0; q < 4; ++q) {                   \
      const float* f0 = (const float*)&xr[q];                         \
      const float* f1 = (const float*)&xr[4 + q];                     \
      _Pragma("unroll") for (int e = 0; e < 4; ++e) {                 \
        c0[4 * q + e] = (f16)f0[e];                                   \
        c1[4 * q + e] = (f16)f1[e];                                   \
      }                                                               \
    }                                                                 \
    _Pragma("unroll") for (int q = 0; q < 4; ++q) {                   \
      f16x4 v0 = {c0[4 * q], c0[4 * q + 1], c0[4 * q + 2], c0[4 * q + 3]}; \
      f16x4 v1 = {c1[4 * q], c1[4 * q + 1], c1[4 * q + 2], c1[4 * q + 3]}; \
      *(f16x4*)&X16[bidx][2 * p][16 * jbk + 4 * q] = v0;              \
      *(f16x4*)&X16[bidx][2 * p + 1][16 * jbk + 4 * q] = v1;          \
    }                                                                 \
    _Pragma("unroll") for (int c = 0; c < 16; ++c) {                  \
      *(u32*)&Xt16[bidx][16 * jbk + c][2 * p] = pk2(c0[c], c1[c]);    \
    }                                                                 \
  }

  // prologue: IO stages x(0) into buf0 and preloads x(1); P-waves tgt(0)+prio
  if (wid >= 4) {
    XLOAD(0);
    XPREP(0);
    XLOAD(1);
  } else {
    __builtin_amdgcn_s_setprio(1);
    tcur = tg[(long)lane * T_N];
  }
  __syncthreads();

  for (int t = 0; t < T_N; ++t) {
    const int pbn = (pb == 2) ? 0 : pb + 1;  // (t+1) % 3
    const int sp = t & 1;                    // pairs parity
    const bool doG = (ft >= FCUT);           // wave-uniform: P-update alive?
    f32x16 acc1[2];  // Px: live across the barrier into phase F

    // ================= phase 1 =================
    if (wid < 4) {
      // tgt prefetch for t+1 (used next step; latency fully covered)
      if (t + 1 < T_N) tnxt = tg[(long)lane * T_N + (t + 1)];

      // ---- hoisted row pointers (one add each; reads use imm offsets)
      const f16* rA0 = &X16[pb][l31][8 * h];
      const f16* rA1 = &X16[pb][32 + l31][8 * h];
      const f16* rQ0 = &X16[pb][l31][32 * w + 4 * h];
      const f16* rQ1 = &X16[pb][32 + l31][32 * w + 4 * h];
      const float* rT = &theta[32 * w + 4 * h];

      // ---- ar first half (ks 0-3), issued before pack so LDS service
      // overlaps pack's VALU (burst-smoothing across the 4 P-waves)
      f16x4 ar[8][4];
#pragma unroll
      for (int ks = 0; ks < 4; ++ks) {
        ar[ks][0] = *(const f16x4*)(rA0 + 16 * ks);
        ar[ks][1] = *(const f16x4*)(rA0 + 16 * ks + 4);
        ar[ks][2] = *(const f16x4*)(rA1 + 16 * ks);
        ar[ks][3] = *(const f16x4*)(rA1 + 16 * ks + 4);
      }

      // ---- (B) pack Pt into f16 pair quads (hi only)
      u32 pqh[4][4][2];
#pragma unroll
      for (int jm = 0; jm < 4; ++jm)
#pragma unroll
        for (int rq = 0; rq < 4; ++rq) {
          pqh[jm][rq][0] = pkrtz(Pacc[jm][4 * rq + 0], Pacc[jm][4 * rq + 1]);
          pqh[jm][rq][1] = pkrtz(Pacc[jm][4 * rq + 2], Pacc[jm][4 * rq + 3]);
        }

      // ---- ar second half + D-phase xq/tq (needed only late, in D)
#pragma unroll
      for (int ks = 4; ks < 8; ++ks) {
        ar[ks][0] = *(const f16x4*)(rA0 + 16 * ks);
        ar[ks][1] = *(const f16x4*)(rA0 + 16 * ks + 4);
        ar[ks][2] = *(const f16x4*)(rA1 + 16 * ks);
        ar[ks][3] = *(const f16x4*)(rA1 + 16 * ks + 4);
      }
      f16x4 xq[2][4];
      float4 tq[4];
#pragma unroll
      for (int rq = 0; rq < 4; ++rq) {
        tq[rq] = *(const float4*)(rT + 8 * rq);
        xq[0][rq] = *(const f16x4*)(rQ0 + 8 * rq);
        xq[1][rq] = *(const f16x4*)(rQ1 + 8 * rq);
      }

      // ---- (C) m1: acc1 = X*Pt^T  and  m1': accT = Pt*X^T (for q,y reduction)
      f32x16 accT[2];
#pragma unroll
      for (int ks = 0; ks < 8; ++ks) {
        const int a = ks >> 1, s = 2 * (ks & 1);
        f16x8 bh = bfrag(h, pqh[a][s][0], pqh[a][s][1], pqh[a][s + 1][0], pqh[a][s + 1][1]);
        f16x8 a0 = cat8(ar[ks][0], ar[ks][1]);
        f16x8 a1 = cat8(ar[ks][2], ar[ks][3]);
        if (ks == 0) {
          acc1[0] = __builtin_amdgcn_mfma_f32_32x32x16_f16(a0, bh, Z, 0, 0, 0);
          acc1[1] = __builtin_amdgcn_mfma_f32_32x32x16_f16(a1, bh, Z, 0, 0, 0);
          accT[0] = __builtin_amdgcn_mfma_f32_32x32x16_f16(bh, a0, Z, 0, 0, 0);
          accT[1] = __builtin_amdgcn_mfma_f32_32x32x16_f16(bh, a1, Z, 0, 0, 0);
        } else {
          acc1[0] = __builtin_amdgcn_mfma_f32_32x32x16_f16(a0, bh, acc1[0], 0, 0, 0);
          acc1[1] = __builtin_amdgcn_mfma_f32_32x32x16_f16(a1, bh, acc1[1], 0, 0, 0);
          accT[0] = __builtin_amdgcn_mfma_f32_32x32x16_f16(bh, a0, accT[0], 0, 0, 0);
          accT[1] = __builtin_amdgcn_mfma_f32_32x32x16_f16(bh, a1, accT[1], 0, 0, 0);
        }
      }

      // ---- (D) q = x'Ptx, y = x'theta per b: in-lane over regs (i), one
      // permlane half-sum, one LDS write per (wave,b).
#pragma unroll
      for (int bt = 0; bt < 2; ++bt) {
        float q = 0.0f, y = 0.0f;
#pragma unroll
        for (int rq = 0; rq < 4; ++rq) {
          const float* tqf = (const float*)&tq[rq];
#pragma unroll
          for (int c = 0; c < 4; ++c) {
            const float xf = (float)xq[bt][rq][c];
            q = fmaf(xf, accT[bt][4 * rq + c], q);
            y = fmaf(xf, tqf[c], y);
          }
        }
        q = hsum32(q);
        y = hsum32(y);
        if (h == 0) {
          float2 v; v.x = q; v.y = y;
          *(float2*)&pairs[sp][w][32 * bt + l31][0] = v;
        }
      }
    } else {
      // IO: stage x(t+1) into buf (t+1)%3 (vmcnt wait ~0: loaded a full step
      // ago), then issue the x(t+2) loads (stay in flight across the barrier)
      if (t + 1 < T_N) XPREP(pbn);
      if (t + 2 < T_N) XLOAD(t + 2);
    }
    wg_barrier();

    // ================= phase 2 =================
    if (wid < 4) {
      // ---- (1) pairs reads FIRST (in-order LDS return: E' starts earliest)
      float2 pv[4];
#pragma unroll
      for (int ww = 0; ww < 4; ++ww)
        pv[ww] = *(const float2*)&pairs[sp][ww][lane][0];

      // ---- (2) E': per-lane b=lane; fold negsc into rd -> rdm
      {
        const float qs = pv[0].x + pv[1].x + pv[2].x + pv[3].x;
        const float ys = pv[0].y + pv[1].y + pv[2].y + pv[3].y;
        const float rd = __builtin_amdgcn_rcpf(qs + FEPS * ft);  // 1e-7 rel
        const float rdm = rd * (-ft * INVB);                     // rd * negsc
        float2 v2; v2.x = rdm; v2.y = tcur - ys;
        *(float2*)&rw[w][lane][0] = v2;
      }

      // ---- (3) hoisted rw gather (16 float4) BEFORE any xt reads, so F's
      // operands are not queued behind 32 xt returns (in-order LDS pipe)
      float4 rwq[2][4][2];
#pragma unroll
      for (int bm = 0; bm < 2; ++bm)
#pragma unroll
        for (int rq = 0; rq < 4; ++rq) {
          const int b0 = 32 * bm + 8 * rq + 4 * h;
          rwq[bm][rq][0] = *(const float4*)&rw[w][b0][0];
          rwq[bm][rq][1] = *(const float4*)&rw[w][b0 + 2][0];
        }
      __builtin_amdgcn_sched_barrier(0);  // pin: rw gather issues before xt

      // ---- (4) xt reads for G ks=0,1 — only while the P-update is alive
      const f16* rXt[4];
#pragma unroll
      for (int jm = 0; jm < 4; ++jm) rXt[jm] = &Xt16[pb][32 * jm + l31][8 * h];
      f16x4 xt01[2][4][2];
      if (doG) {
#pragma unroll
        for (int ks = 0; ks < 2; ++ks)
#pragma unroll
          for (int jm = 0; jm < 4; ++jm) {
            xt01[ks][jm][0] = *(const f16x4*)(rXt[jm] + 16 * ks);
            xt01[ks][jm][1] = *(const f16x4*)(rXt[jm] + 16 * ks + 4);
          }
      }

      // ---- (F) km = acc1*rdm (pre-folded), tsum over km*err; kq pack only
      // while alive (km underflows the f16 denormal floor when !doG)
      u32 kq[2][4][2];
      float tsum = 0.0f;
#pragma unroll
      for (int bm = 0; bm < 2; ++bm)
#pragma unroll
        for (int rq = 0; rq < 4; ++rq) {
          const float4 qa = rwq[bm][rq][0];  // rdm0,e0,rdm1,e1
          const float4 qb = rwq[bm][rq][1];  // rdm2,e2,rdm3,e3
          const float km0 = acc1[bm][4 * rq + 0] * qa.x;
          const float km1 = acc1[bm][4 * rq + 1] * qa.z;
          const float km2 = acc1[bm][4 * rq + 2] * qb.x;
          const float km3 = acc1[bm][4 * rq + 3] * qb.z;
          tsum += km0 * qa.y + km1 * qa.w + km2 * qb.y + km3 * qb.w;
          if (doG) {
            kq[bm][rq][0] = pkrtz(km0, km1);
            kq[bm][rq][1] = pkrtz(km2, km3);
          }
        }
      tsum = hsum32(tsum);
      // theta delta = mean_b(K err) = tsum * (-1/ft)  (km = -ft/64 * K)
      const float negftinv = -__builtin_amdgcn_rcpf(ft);
      if (h == 0) theta[i32] = fmaf(tsum, negftinv, theta[i32]);

      // ---- (G) m2: Pt += Xt * km, rolling xt reads for ks=2,3 (skippable)
      if (doG) {
        f16x4 xt2[4][2], xt3[4][2];
#pragma unroll
        for (int jm = 0; jm < 4; ++jm) {
          xt2[jm][0] = *(const f16x4*)(rXt[jm] + 32);
          xt2[jm][1] = *(const f16x4*)(rXt[jm] + 36);
        }
        {  // ks = 0
          f16x8 bh = bfrag(h, kq[0][0][0], kq[0][0][1], kq[0][1][0], kq[0][1][1]);
#pragma unroll
          for (int jm = 0; jm < 4; ++jm)
            Pacc[jm] = __builtin_amdgcn_mfma_f32_32x32x16_f16(
                cat8(xt01[0][jm][0], xt01[0][jm][1]), bh, Pacc[jm], 0, 0, 0);
        }
#pragma unroll
        for (int jm = 0; jm < 4; ++jm) {
          xt3[jm][0] = *(const f16x4*)(rXt[jm] + 48);
          xt3[jm][1] = *(const f16x4*)(rXt[jm] + 52);
        }
        {  // ks = 1
          f16x8 bh = bfrag(h, kq[0][2][0], kq[0][2][1], kq[0][3][0], kq[0][3][1]);
#pragma unroll
          for (int jm = 0; jm < 4; ++jm)
            Pacc[jm] = __builtin_amdgcn_mfma_f32_32x32x16_f16(
                cat8(xt01[1][jm][0], xt01[1][jm][1]), bh, Pacc[jm], 0, 0, 0);
        }
        {  // ks = 2
          f16x8 bh = bfrag(h, kq[1][0][0], kq[1][0][1], kq[1][1][0], kq[1][1][1]);
#pragma unroll
          for (int jm = 0; jm < 4; ++jm)
            Pacc[jm] = __builtin_amdgcn_mfma_f32_32x32x16_f16(
                cat8(xt2[jm][0], xt2[jm][1]), bh, Pacc[jm], 0, 0, 0);
        }
        {  // ks = 3
          f16x8 bh = bfrag(h, kq[1][2][0], kq[1][2][1], kq[1][3][0], kq[1][3][1]);
#pragma unroll
          for (int jm = 0; jm < 4; ++jm)
            Pacc[jm] = __builtin_amdgcn_mfma_f32_32x32x16_f16(
                cat8(xt3[jm][0], xt3[jm][1]), bh, Pacc[jm], 0, 0, 0);
        }
      }
      tcur = tnxt;
    } else if (wid == 4) {
      // IO wave 4: redundant ys-sum, store raw attention (overlapped with F/G)
      float ys = 0.0f;
#pragma unroll
      for (int ww = 0; ww < 4; ++ww) ys += pairs[sp][ww][lane][1];
      attn[(long)lane * T_N + t] = ys;
    }
    // NO end-of-step barrier (R11 race audit: triple-buffered X, parity pairs)

    pb = pbn;
    ft *= FF;
  }
#undef XLOAD
#undef XPREP
}

// softmax over time per batch row (in place on raw attn)
__global__ void softmax_k(float* __restrict__ attn) {
  const int b = blockIdx.x;
  float* row = attn + (long)b * T_N;
  __shared__ float sv[T_N];
  __shared__ float red[256];
  const int tid = threadIdx.x;
  float m = -1e30f;
  for (int k = tid; k < T_N; k += 256) {
    const float v = row[k];
    sv[k] = v;
    m = fmaxf(m, v);
  }
  red[tid] = m;
  __syncthreads();
  for (int off = 128; off > 0; off >>= 1) {
    if (tid < off) red[tid] = fmaxf(red[tid], red[tid + off]);
    __syncthreads();
  }
  const float M = red[0];
  __syncthreads();
  float s = 0.0f;
  for (int k = tid; k < T_N; k += 256) {
    const float e = __expf(sv[k] - M);
    sv[k] = e;
    s += e;
  }
  red[tid] = s;
  __syncthreads();
  for (int off = 128; off > 0; off >>= 1) {
    if (tid < off) red[tid] += red[tid + off];
    __syncthreads();
  }
  const float inv = 1.0f / red[0];
  for (int k = tid; k < T_N; k += 256) row[k] = sv[k] * inv;
}

// out[b][d] = sum_t x[b][t][d] * attn_norm[b][t]
__global__ void einsum_k(const float* __restrict__ xg,
                         const float* __restrict__ attn,
                         float* __restrict__ out) {
  const int b = blockIdx.x;
  const int d = threadIdx.x;  // 128 threads
  __shared__ float as[T_N];
  for (int k = d; k < T_N; k += 128) as[k] = attn[(long)b * T_N + k];
  __syncthreads();
  const float* xb = xg + (long)b * T_N * D_N + d;
  float acc = 0.0f;
#pragma unroll 4
  for (int t = 0; t < T_N; ++t) acc += xb[(long)t * D_N] * as[t];
  out[b * D_N + d] = acc;
}

extern "C" void kernel_launch(void* const* d_in, const int* in_sizes, int n_in,
                              void* d_out, int out_size, void* d_ws, size_t ws_size,
                              hipStream_t stream) {
  const float* x = (const float*)d_in[0];
  const float* tgt = (const float*)d_in[1];
  float* out = (float*)d_out;
  float* attn = out + B_N * D_N;  // outputs: [output (B,D) | attn_norm (B,T)]

  rls_seq<<<dim3(1), dim3(512), 0, stream>>>(x, tgt, attn);
  softmax_k<<<dim3(B_N), dim3(256), 0, stream>>>(attn);
  einsum_k<<<dim3(B_N), dim3(128), 0, stream>>>(x, attn, out);
}

// Round 17
// 9303.560 us; speedup vs baseline: 1.3087x; 1.3087x over previous
//
#include <hip/hip_runtime.h>

#define T_N 4096
#define B_N 64
#define D_N 128
#define T_CUT 1240  // ft < ~4e-6 beyond here: P-update MFMAs add ~denormal-zero

typedef _Float16 f16;
typedef _Float16 f16x4 __attribute__((ext_vector_type(4)));
typedef _Float16 f16x8 __attribute__((ext_vector_type(8)));
typedef __fp16 fp16x2 __attribute__((ext_vector_type(2)));
typedef float f32x16 __attribute__((ext_vector_type(16)));
typedef unsigned int u32;
typedef unsigned int u32x2 __attribute__((ext_vector_type(2)));

__device__ __forceinline__ f16x8 cat8(f16x4 a, f16x4 b) {
  return __builtin_shufflevector(a, b, 0, 1, 2, 3, 4, 5, 6, 7);
}
__device__ __forceinline__ u32 pk2(f16 a, f16 b) {
  union { f16 x[2]; u32 u; } z;
  z.x[0] = a; z.x[1] = b;
  return z.u;
}
__device__ __forceinline__ u32 pkrtz(float a, float b) {
  union { fp16x2 h; u32 u; } z;
  z.h = __builtin_amdgcn_cvt_pkrtz(a, b);
  return z.u;
}
// own + partner-half value, branchless (HW-verified in R11).
__device__ __forceinline__ float hsum32(float v) {
  union { float f; u32 u; } a; a.f = v;
  u32x2 r = __builtin_amdgcn_permlane32_swap(a.u, a.u, false, false);
  union { u32 u; float f; } o0, o1;
  o0.u = r[0]; o1.u = r[1];
  return o0.f + o1.f;
}

// raw barrier: LDS-visibility only; does NOT drain vmcnt (prefetch stays in flight)
__device__ __forceinline__ void wg_barrier() {
  asm volatile("s_waitcnt lgkmcnt(0)" ::: "memory");
  __builtin_amdgcn_sched_barrier(0);
  __builtin_amdgcn_s_barrier();
  __builtin_amdgcn_sched_barrier(0);
}

// B/A fragment builder (k-slot layout empirically verified end-to-end vs CPU
// reference across m1/m1'/m2 with random data, rounds 5-15).
__device__ __forceinline__ f16x8 bfrag(int h, u32 qs0, u32 qs1, u32 qt0, u32 qt1) {
  u32x2 s0 = __builtin_amdgcn_permlane32_swap(qs0, qt0, false, false);
  u32x2 s1 = __builtin_amdgcn_permlane32_swap(qs1, qt1, false, false);
  union { u32 u[4]; f16x8 v; } z;
  z.u[0] = s0[0]; z.u[1] = s1[0]; z.u[2] = s0[1]; z.u[3] = s1[1];
  return z.v;
}

// Sequential RLS scan, single-barrier pipeline (R15 champion structure),
// LOOP-SPLIT ft-freeze: loop 1 (t < T_CUT) runs the full recurrence; loop 2
// (t >= T_CUT) statically drops the P-update (kq pack + xt reads + G MFMAs),
// whose km contributions are at/below the f16-denormal floor (R16 measured:
// absmax bit-identical with the update skipped; R16's per-iteration branch
// form wrecked compiler scheduling -> split into two branch-free loops).
// Loop 2's theta path is ft-free: s_b = rd*err/64, theta += sum_b acc1*s_b.
__global__ __launch_bounds__(512, 1) void rls_seq(
    const float* __restrict__ xg, const float* __restrict__ tg,
    float* __restrict__ attn) {
  constexpr float FF = 0.99f, EPS = 1e-8f;
  constexpr float FEPS = FF + EPS;
  constexpr float INVB = 1.0f / 64.0f;

  // u32-strides mod 4 == 2 -> 2-way (free) bank aliasing
  __shared__ alignas(16) f16 X16[3][64][132];    // x16[b][j]
  __shared__ alignas(16) f16 Xt16[3][128][68];   // x16[b][j] stored [j][b]
  __shared__ alignas(16) float theta[128];
  __shared__ alignas(16) float pairs[2][4][64][2];  // per-step-parity (q,y) partials
  __shared__ alignas(16) float rw[4][64][2];        // per-P-wave private scalars

  const int tid = threadIdx.x;
  const int wid = tid >> 6;       // 0..3 P-waves, 4..7 IO-waves
  const int lane = tid & 63;
  const int l31 = lane & 31;
  const int h = lane >> 5;
  const int w = wid & 3;          // P: owned i-tile. IO: staging column group.
  const int i32 = 32 * w + l31;   // P-wave: this lane's P row index i

  // Pacc tile jm, element r  <->  Pt[i32][j], j = 32*jm + (r&3) + 8*(r>>2) + 4*h
  f32x16 Pacc[4];
  if (wid < 4) {
#pragma unroll
    for (int jm = 0; jm < 4; ++jm)
#pragma unroll
      for (int r = 0; r < 16; ++r) {
        const int j = 32 * jm + (r & 3) + 8 * (r >> 2) + 4 * h;
        Pacc[jm][r] = (j == i32) ? 100.0f : 0.0f;  // P0 = I/lambda, ft0 = 1
      }
    if (tid < 128) theta[tid] = 0.0f;
  }

  // staging mapping (IO-waves): thread covers rows (2p,2p+1), cols 16*jbk..+15
  const int p = l31;
  const int jbk = 2 * w + h;
  const long rstride = (long)T_N * D_N;
  const float* xrow0 = xg + (long)(2 * p) * rstride + 16 * jbk;

  float4 xr[8];
  float tcur = 0.0f, tnxt = 0.0f;
  float ft = 1.0f;  // FF^t
  int pb = 0;       // t % 3

  f32x16 Z;  // persistent zero accumulator
#pragma unroll
  for (int r = 0; r < 16; ++r) Z[r] = 0.0f;

#define XLOAD(tt)                                                     \
  {                                                                   \
    _Pragma("unroll") for (int q = 0; q < 4; ++q) {                   \
      xr[q] = *(const float4*)(xrow0 + (long)(tt)*D_N + 4 * q);       \
      xr[4 + q] = *(const float4*)(xrow0 + rstride + (long)(tt)*D_N + 4 * q); \
    }                                                                 \
  }

#define XPREP(bidx)                                                   \
  {                                                                   \
    f16 c0[16], c1[16];                                               \
    _Pragma("unroll") for (int q = 0; q < 4; ++q) {                   \
      const float* f0 = (const float*)&xr[q];                         \
      const float* f1 = (const float*)&xr[4 + q];                     \
      _Pragma("unroll") for (int e = 0; e < 4; ++e) {                 \
        c0[4 * q + e] = (f16)f0[e];                                   \
        c1[4 * q + e] = (f16)f1[e];                                   \
      }                                                               \
    }                                                                 \
    _Pragma("unroll") for (int q = 0; q < 4; ++q) {                   \
      f16x4 v0 = {c0[4 * q], c0[4 * q + 1], c0[4 * q + 2], c0[4 * q + 3]}; \
      f16x4 v1 = {c1[4 * q], c1[4 * q + 1], c1[4 * q + 2], c1[4 * q + 3]}; \
      *(f16x4*)&X16[bidx][2 * p][16 * jbk + 4 * q] = v0;              \
      *(f16x4*)&X16[bidx][2 * p + 1][16 * jbk + 4 * q] = v1;          \
    }                                                                 \
    _Pragma("unroll") for (int c = 0; c < 16; ++c) {                  \
      *(u32*)&Xt16[bidx][16 * jbk + c][2 * p] = pk2(c0[c], c1[c]);    \
    }                                                                 \
  }

// Phase 1 (shared by both loops): pack + m1/m1' + D reduction, or IO staging.
#define PHASE1()                                                              \
  if (wid < 4) {                                                              \
    if (t + 1 < T_N) tnxt = tg[(long)lane * T_N + (t + 1)];                   \
    const f16* rA0 = &X16[pb][l31][8 * h];                                    \
    const f16* rA1 = &X16[pb][32 + l31][8 * h];                               \
    const f16* rQ0 = &X16[pb][l31][32 * w + 4 * h];                           \
    const f16* rQ1 = &X16[pb][32 + l31][32 * w + 4 * h];                      \
    const float* rT = &theta[32 * w + 4 * h];                                 \
    f16x4 ar[8][4];                                                           \
    _Pragma("unroll") for (int ks = 0; ks < 4; ++ks) {                        \
      ar[ks][0] = *(const f16x4*)(rA0 + 16 * ks);                             \
      ar[ks][1] = *(const f16x4*)(rA0 + 16 * ks + 4);                         \
      ar[ks][2] = *(const f16x4*)(rA1 + 16 * ks);                             \
      ar[ks][3] = *(const f16x4*)(rA1 + 16 * ks + 4);                         \
    }                                                                         \
    u32 pqh[4][4][2];                                                         \
    _Pragma("unroll") for (int jm = 0; jm < 4; ++jm)                          \
      _Pragma("unroll") for (int rq = 0; rq < 4; ++rq) {                      \
        pqh[jm][rq][0] = pkrtz(Pacc[jm][4 * rq + 0], Pacc[jm][4 * rq + 1]);   \
        pqh[jm][rq][1] = pkrtz(Pacc[jm][4 * rq + 2], Pacc[jm][4 * rq + 3]);   \
      }                                                                       \
    _Pragma("unroll") for (int ks = 4; ks < 8; ++ks) {                        \
      ar[ks][0] = *(const f16x4*)(rA0 + 16 * ks);                             \
      ar[ks][1] = *(const f16x4*)(rA0 + 16 * ks + 4);                         \
      ar[ks][2] = *(const f16x4*)(rA1 + 16 * ks);                             \
      ar[ks][3] = *(const f16x4*)(rA1 + 16 * ks + 4);                         \
    }                                                                         \
    f16x4 xq[2][4];                                                           \
    float4 tq[4];                                                             \
    _Pragma("unroll") for (int rq = 0; rq < 4; ++rq) {                        \
      tq[rq] = *(const float4*)(rT + 8 * rq);                                 \
      xq[0][rq] = *(const f16x4*)(rQ0 + 8 * rq);                              \
      xq[1][rq] = *(const f16x4*)(rQ1 + 8 * rq);                              \
    }                                                                         \
    f32x16 accT[2];                                                           \
    _Pragma("unroll") for (int ks = 0; ks < 8; ++ks) {                        \
      const int a = ks >> 1, s = 2 * (ks & 1);                                \
      f16x8 bh = bfrag(h, pqh[a][s][0], pqh[a][s][1], pqh[a][s + 1][0],       \
                       pqh[a][s + 1][1]);                                     \
      f16x8 a0 = cat8(ar[ks][0], ar[ks][1]);                                  \
      f16x8 a1 = cat8(ar[ks][2], ar[ks][3]);                                  \
      if (ks == 0) {                                                          \
        acc1[0] = __builtin_amdgcn_mfma_f32_32x32x16_f16(a0, bh, Z, 0, 0, 0); \
        acc1[1] = __builtin_amdgcn_mfma_f32_32x32x16_f16(a1, bh, Z, 0, 0, 0); \
        accT[0] = __builtin_amdgcn_mfma_f32_32x32x16_f16(bh, a0, Z, 0, 0, 0); \
        accT[1] = __builtin_amdgcn_mfma_f32_32x32x16_f16(bh, a1, Z, 0, 0, 0); \
      } else {                                                                \
        acc1[0] = __builtin_amdgcn_mfma_f32_32x32x16_f16(a0, bh, acc1[0], 0, 0, 0); \
        acc1[1] = __builtin_amdgcn_mfma_f32_32x32x16_f16(a1, bh, acc1[1], 0, 0, 0); \
        accT[0] = __builtin_amdgcn_mfma_f32_32x32x16_f16(bh, a0, accT[0], 0, 0, 0); \
        accT[1] = __builtin_amdgcn_mfma_f32_32x32x16_f16(bh, a1, accT[1], 0, 0, 0); \
      }                                                                       \
    }                                                                         \
    _Pragma("unroll") for (int bt = 0; bt < 2; ++bt) {                        \
      float q = 0.0f, y = 0.0f;                                               \
      _Pragma("unroll") for (int rq = 0; rq < 4; ++rq) {                      \
        const float* tqf = (const float*)&tq[rq];                             \
        _Pragma("unroll") for (int c = 0; c < 4; ++c) {                       \
          const float xf = (float)xq[bt][rq][c];                              \
          q = fmaf(xf, accT[bt][4 * rq + c], q);                              \
          y = fmaf(xf, tqf[c], y);                                            \
        }                                                                     \
      }                                                                       \
      q = hsum32(q);                                                          \
      y = hsum32(y);                                                          \
      if (h == 0) {                                                           \
        float2 v; v.x = q; v.y = y;                                           \
        *(float2*)&pairs[sp][w][32 * bt + l31][0] = v;                        \
      }                                                                       \
    }                                                                         \
  } else {                                                                    \
    if (t + 1 < T_N) XPREP(pbn);                                              \
    if (t + 2 < T_N) XLOAD(t + 2);                                            \
  }

#define IOW4_ATTN()                                                           \
  {                                                                           \
    float ys = 0.0f;                                                          \
    _Pragma("unroll") for (int ww = 0; ww < 4; ++ww)                          \
      ys += pairs[sp][ww][lane][1];                                           \
    attn[(long)lane * T_N + t] = ys;                                          \
  }

  // prologue: IO stages x(0) into buf0 and preloads x(1); P-waves tgt(0)+prio
  if (wid >= 4) {
    XLOAD(0);
    XPREP(0);
    XLOAD(1);
  } else {
    __builtin_amdgcn_s_setprio(1);
    tcur = tg[(long)lane * T_N];
  }
  __syncthreads();

  // ======================= LOOP 1: full recurrence =======================
  for (int t = 0; t < T_CUT; ++t) {
    const int pbn = (pb == 2) ? 0 : pb + 1;  // (t+1) % 3
    const int sp = t & 1;                    // pairs parity
    f32x16 acc1[2];  // Px: live across the barrier into phase F

    PHASE1();
    wg_barrier();

    // ---------------- phase 2 (full: E' + F + G) ----------------
    if (wid < 4) {
      float2 pv[4];
#pragma unroll
      for (int ww = 0; ww < 4; ++ww)
        pv[ww] = *(const float2*)&pairs[sp][ww][lane][0];

      {
        const float qs = pv[0].x + pv[1].x + pv[2].x + pv[3].x;
        const float ys = pv[0].y + pv[1].y + pv[2].y + pv[3].y;
        const float rd = __builtin_amdgcn_rcpf(qs + FEPS * ft);  // 1e-7 rel
        const float rdm = rd * (-ft * INVB);                     // rd * negsc
        float2 v2; v2.x = rdm; v2.y = tcur - ys;
        *(float2*)&rw[w][lane][0] = v2;
      }

      float4 rwq[2][4][2];
#pragma unroll
      for (int bm = 0; bm < 2; ++bm)
#pragma unroll
        for (int rq = 0; rq < 4; ++rq) {
          const int b0 = 32 * bm + 8 * rq + 4 * h;
          rwq[bm][rq][0] = *(const float4*)&rw[w][b0][0];
          rwq[bm][rq][1] = *(const float4*)&rw[w][b0 + 2][0];
        }
      __builtin_amdgcn_sched_barrier(0);  // pin: rw gather issues before xt

      const f16* rXt[4];
#pragma unroll
      for (int jm = 0; jm < 4; ++jm) rXt[jm] = &Xt16[pb][32 * jm + l31][8 * h];
      f16x4 xt01[2][4][2];
#pragma unroll
      for (int ks = 0; ks < 2; ++ks)
#pragma unroll
        for (int jm = 0; jm < 4; ++jm) {
          xt01[ks][jm][0] = *(const f16x4*)(rXt[jm] + 16 * ks);
          xt01[ks][jm][1] = *(const f16x4*)(rXt[jm] + 16 * ks + 4);
        }

      u32 kq[2][4][2];
      float tsum = 0.0f;
#pragma unroll
      for (int bm = 0; bm < 2; ++bm)
#pragma unroll
        for (int rq = 0; rq < 4; ++rq) {
          const float4 qa = rwq[bm][rq][0];  // rdm0,e0,rdm1,e1
          const float4 qb = rwq[bm][rq][1];  // rdm2,e2,rdm3,e3
          const float km0 = acc1[bm][4 * rq + 0] * qa.x;
          const float km1 = acc1[bm][4 * rq + 1] * qa.z;
          const float km2 = acc1[bm][4 * rq + 2] * qb.x;
          const float km3 = acc1[bm][4 * rq + 3] * qb.z;
          tsum += km0 * qa.y + km1 * qa.w + km2 * qb.y + km3 * qb.w;
          kq[bm][rq][0] = pkrtz(km0, km1);
          kq[bm][rq][1] = pkrtz(km2, km3);
        }
      tsum = hsum32(tsum);
      const float negftinv = -__builtin_amdgcn_rcpf(ft);
      if (h == 0) theta[i32] = fmaf(tsum, negftinv, theta[i32]);

      f16x4 xt2[4][2], xt3[4][2];
#pragma unroll
      for (int jm = 0; jm < 4; ++jm) {
        xt2[jm][0] = *(const f16x4*)(rXt[jm] + 32);
        xt2[jm][1] = *(const f16x4*)(rXt[jm] + 36);
      }
      {  // ks = 0
        f16x8 bh = bfrag(h, kq[0][0][0], kq[0][0][1], kq[0][1][0], kq[0][1][1]);
#pragma unroll
        for (int jm = 0; jm < 4; ++jm)
          Pacc[jm] = __builtin_amdgcn_mfma_f32_32x32x16_f16(
              cat8(xt01[0][jm][0], xt01[0][jm][1]), bh, Pacc[jm], 0, 0, 0);
      }
#pragma unroll
      for (int jm = 0; jm < 4; ++jm) {
        xt3[jm][0] = *(const f16x4*)(rXt[jm] + 48);
        xt3[jm][1] = *(const f16x4*)(rXt[jm] + 52);
      }
      {  // ks = 1
        f16x8 bh = bfrag(h, kq[0][2][0], kq[0][2][1], kq[0][3][0], kq[0][3][1]);
#pragma unroll
        for (int jm = 0; jm < 4; ++jm)
          Pacc[jm] = __builtin_amdgcn_mfma_f32_32x32x16_f16(
              cat8(xt01[1][jm][0], xt01[1][jm][1]), bh, Pacc[jm], 0, 0, 0);
      }
      {  // ks = 2
        f16x8 bh = bfrag(h, kq[1][0][0], kq[1][0][1], kq[1][1][0], kq[1][1][1]);
#pragma unroll
        for (int jm = 0; jm < 4; ++jm)
          Pacc[jm] = __builtin_amdgcn_mfma_f32_32x32x16_f16(
              cat8(xt2[jm][0], xt2[jm][1]), bh, Pacc[jm], 0, 0, 0);
      }
      {  // ks = 3
        f16x8 bh = bfrag(h, kq[1][2][0], kq[1][2][1], kq[1][3][0], kq[1][3][1]);
#pragma unroll
        for (int jm = 0; jm < 4; ++jm)
          Pacc[jm] = __builtin_amdgcn_mfma_f32_32x32x16_f16(
              cat8(xt3[jm][0], xt3[jm][1]), bh, Pacc[jm], 0, 0, 0);
      }
      tcur = tnxt;
    } else if (wid == 4) {
      IOW4_ATTN();
    }
    pb = pbn;
    ft *= FF;
  }

  // ============== LOOP 2: frozen P (no kq/xt/G), ft-free theta ==============
  for (int t = T_CUT; t < T_N; ++t) {
    const int pbn = (pb == 2) ? 0 : pb + 1;  // (t+1) % 3
    const int sp = t & 1;                    // pairs parity
    f32x16 acc1[2];

    PHASE1();
    wg_barrier();

    // ---------------- phase 2 (E' + theta only) ----------------
    if (wid < 4) {
      float2 pv[4];
#pragma unroll
      for (int ww = 0; ww < 4; ++ww)
        pv[ww] = *(const float2*)&pairs[sp][ww][lane][0];

      {
        const float qs = pv[0].x + pv[1].x + pv[2].x + pv[3].x;
        const float ys = pv[0].y + pv[1].y + pv[2].y + pv[3].y;
        const float rd = __builtin_amdgcn_rcpf(qs + FEPS * ft);
        // s_b = rd*err/64: theta += sum_b acc1_b * s_b  (ft-free path)
        float2 v2; v2.x = rd * (tcur - ys) * INVB; v2.y = 0.0f;
        *(float2*)&rw[w][lane][0] = v2;
      }

      float4 rwq[2][4][2];
#pragma unroll
      for (int bm = 0; bm < 2; ++bm)
#pragma unroll
        for (int rq = 0; rq < 4; ++rq) {
          const int b0 = 32 * bm + 8 * rq + 4 * h;
          rwq[bm][rq][0] = *(const float4*)&rw[w][b0][0];
          rwq[bm][rq][1] = *(const float4*)&rw[w][b0 + 2][0];
        }

      float tsum = 0.0f;
#pragma unroll
      for (int bm = 0; bm < 2; ++bm)
#pragma unroll
        for (int rq = 0; rq < 4; ++rq) {
          const float4 qa = rwq[bm][rq][0];  // s0,_,s1,_
          const float4 qb = rwq[bm][rq][1];  // s2,_,s3,_
          tsum = fmaf(acc1[bm][4 * rq + 0], qa.x,
                 fmaf(acc1[bm][4 * rq + 1], qa.z,
                 fmaf(acc1[bm][4 * rq + 2], qb.x,
                 fmaf(acc1[bm][4 * rq + 3], qb.z, tsum))));
        }
      tsum = hsum32(tsum);
      if (h == 0) theta[i32] += tsum;
      tcur = tnxt;
    } else if (wid == 4) {
      IOW4_ATTN();
    }
    pb = pbn;
    ft *= FF;
  }
#undef XLOAD
#undef XPREP
#undef PHASE1
#undef IOW4_ATTN
}

// softmax over time per batch row (in place on raw attn)
__global__ void softmax_k(float* __restrict__ attn) {
  const int b = blockIdx.x;
  float* row = attn + (long)b * T_N;
  __shared__ float sv[T_N];
  __shared__ float red[256];
  const int tid = threadIdx.x;
  float m = -1e30f;
  for (int k = tid; k < T_N; k += 256) {
    const float v = row[k];
    sv[k] = v;
    m = fmaxf(m, v);
  }
  red[tid] = m;
  __syncthreads();
  for (int off = 128; off > 0; off >>= 1) {
    if (tid < off) red[tid] = fmaxf(red[tid], red[tid + off]);
    __syncthreads();
  }
  const float M = red[0];
  __syncthreads();
  float s = 0.0f;
  for (int k = tid; k < T_N; k += 256) {
    const float e = __expf(sv[k] - M);
    sv[k] = e;
    s += e;
  }
  red[tid] = s;
  __syncthreads();
  for (int off = 128; off > 0; off >>= 1) {
    if (tid < off) red[tid] += red[tid + off];
    __syncthreads();
  }
  const float inv = 1.0f / red[0];
  for (int k = tid; k < T_N; k += 256) row[k] = sv[k] * inv;
}

// out[b][d] = sum_t x[b][t][d] * attn_norm[b][t]
__global__ void einsum_k(const float* __restrict__ xg,
                         const float* __restrict__ attn,
                         float* __restrict__ out) {
  const int b = blockIdx.x;
  const int d = threadIdx.x;  // 128 threads
  __shared__ float as[T_N];
  for (int k = d; k < T_N; k += 128) as[k] = attn[(long)b * T_N + k];
  __syncthreads();
  const float* xb = xg + (long)b * T_N * D_N + d;
  float acc = 0.0f;
#pragma unroll 4
  for (int t = 0; t < T_N; ++t) acc += xb[(long)t * D_N] * as[t];
  out[b * D_N + d] = acc;
}

extern "C" void kernel_launch(void* const* d_in, const int* in_sizes, int n_in,
                              void* d_out, int out_size, void* d_ws, size_t ws_size,
                              hipStream_t stream) {
  const float* x = (const float*)d_in[0];
  const float* tgt = (const float*)d_in[1];
  float* out = (float*)d_out;
  float* attn = out + B_N * D_N;  // outputs: [output (B,D) | attn_norm (B,T)]

  rls_seq<<<dim3(1), dim3(512), 0, stream>>>(x, tgt, attn);
  softmax_k<<<dim3(B_N), dim3(256), 0, stream>>>(attn);
  einsum_k<<<dim3(B_N), dim3(128), 0, stream>>>(x, attn, out);
}

// Round 18
// 7505.865 us; speedup vs baseline: 1.6222x; 1.2395x over previous
//
#include <hip/hip_runtime.h>

#define T_N 4096
#define B_N 64
#define D_N 128

typedef _Float16 f16;
typedef _Float16 f16x4 __attribute__((ext_vector_type(4)));
typedef _Float16 f16x8 __attribute__((ext_vector_type(8)));
typedef __fp16 fp16x2 __attribute__((ext_vector_type(2)));
typedef float f32x16 __attribute__((ext_vector_type(16)));
typedef unsigned int u32;
typedef unsigned int u32x2 __attribute__((ext_vector_type(2)));

__device__ __forceinline__ f16x8 cat8(f16x4 a, f16x4 b) {
  return __builtin_shufflevector(a, b, 0, 1, 2, 3, 4, 5, 6, 7);
}
__device__ __forceinline__ u32 pk2(f16 a, f16 b) {
  union { f16 x[2]; u32 u; } z;
  z.x[0] = a; z.x[1] = b;
  return z.u;
}
__device__ __forceinline__ u32 pkrtz(float a, float b) {
  union { fp16x2 h; u32 u; } z;
  z.h = __builtin_amdgcn_cvt_pkrtz(a, b);
  return z.u;
}
// own + partner-half value, branchless (HW-verified in R11):
// permlane32_swap(a,a) -> out0 = low-half value, out1 = high-half value for
// every lane, so out0+out1 = own + partner in both halves.
__device__ __forceinline__ float hsum32(float v) {
  union { float f; u32 u; } a; a.f = v;
  u32x2 r = __builtin_amdgcn_permlane32_swap(a.u, a.u, false, false);
  union { u32 u; float f; } o0, o1;
  o0.u = r[0]; o1.u = r[1];
  return o0.f + o1.f;
}

// raw barrier: LDS-visibility only; does NOT drain vmcnt (prefetch stays in flight)
__device__ __forceinline__ void wg_barrier() {
  asm volatile("s_waitcnt lgkmcnt(0)" ::: "memory");
  __builtin_amdgcn_sched_barrier(0);
  __builtin_amdgcn_s_barrier();
  __builtin_amdgcn_sched_barrier(0);
}

// B/A fragment builder (k-slot layout empirically verified end-to-end vs CPU
// reference across m1/m1'/m2 with random data, rounds 5-15).
__device__ __forceinline__ f16x8 bfrag(int h, u32 qs0, u32 qs1, u32 qt0, u32 qt1) {
  u32x2 s0 = __builtin_amdgcn_permlane32_swap(qs0, qt0, false, false);
  u32x2 s1 = __builtin_amdgcn_permlane32_swap(qs1, qt1, false, false);
  union { u32 u[4]; f16x8 v; } z;
  z.u[0] = s0[0]; z.u[1] = s1[0]; z.u[2] = s0[1]; z.u[3] = s1[1];
  return z.v;
}

// Sequential RLS scan, single-barrier pipeline (CHAMPION, round 15):
// 8 waves. Waves 0-3 ("P") hold Pt = FF^t*P in MFMA accumulators; waves 4-7
// ("IO") stage x into a TRIPLE-buffered f16 LDS tile set during phase 1.
// ONE barrier per step (mid-step). Race audit: X/Xt buf k written ph1(k-1),
// read ph1/ph2(k), rewritten ph1(k+2) -> every producer/consumer pair
// crosses >=1 barrier; pairs double-buffered by step parity; theta/rw are
// wave-private with same-wave in-order LDS.
// Measured plateau: attempts to remove work (ft-freeze branch R16, loop-split
// R17), deepen prefetch (R8), or pipeline fragments across the loop edge
// (R13, spilled at 256-reg cap) ALL regressed -> this balance is optimal.
__global__ __launch_bounds__(512, 1) void rls_seq(
    const float* __restrict__ xg, const float* __restrict__ tg,
    float* __restrict__ attn) {
  constexpr float FF = 0.99f, EPS = 1e-8f;
  constexpr float FEPS = FF + EPS;
  constexpr float INVB = 1.0f / 64.0f;

  // u32-strides mod 4 == 2 -> 2-way (free) bank aliasing
  __shared__ alignas(16) f16 X16[3][64][132];    // x16[b][j]
  __shared__ alignas(16) f16 Xt16[3][128][68];   // x16[b][j] stored [j][b]
  __shared__ alignas(16) float theta[128];
  __shared__ alignas(16) float pairs[2][4][64][2];  // per-step-parity (q,y) partials
  __shared__ alignas(16) float rw[4][64][2];        // per-P-wave private (rdm, err)

  const int tid = threadIdx.x;
  const int wid = tid >> 6;       // 0..3 P-waves, 4..7 IO-waves
  const int lane = tid & 63;
  const int l31 = lane & 31;
  const int h = lane >> 5;
  const int w = wid & 3;          // P: owned i-tile. IO: staging column group.
  const int i32 = 32 * w + l31;   // P-wave: this lane's P row index i

  // Pacc tile jm, element r  <->  Pt[i32][j], j = 32*jm + (r&3) + 8*(r>>2) + 4*h
  f32x16 Pacc[4];
  if (wid < 4) {
#pragma unroll
    for (int jm = 0; jm < 4; ++jm)
#pragma unroll
      for (int r = 0; r < 16; ++r) {
        const int j = 32 * jm + (r & 3) + 8 * (r >> 2) + 4 * h;
        Pacc[jm][r] = (j == i32) ? 100.0f : 0.0f;  // P0 = I/lambda, ft0 = 1
      }
    if (tid < 128) theta[tid] = 0.0f;
  }

  // staging mapping (IO-waves): thread covers rows (2p,2p+1), cols 16*jbk..+15
  const int p = l31;
  const int jbk = 2 * w + h;
  const long rstride = (long)T_N * D_N;
  const float* xrow0 = xg + (long)(2 * p) * rstride + 16 * jbk;

  float4 xr[8];
  float tcur = 0.0f, tnxt = 0.0f;
  float ft = 1.0f;  // FF^t
  int pb = 0;       // t % 3

  f32x16 Z;  // persistent zero accumulator
#pragma unroll
  for (int r = 0; r < 16; ++r) Z[r] = 0.0f;

#define XLOAD(tt)                                                     \
  {                                                                   \
    _Pragma("unroll") for (int q = 0; q < 4; ++q) {                   \
      xr[q] = *(const float4*)(xrow0 + (long)(tt)*D_N + 4 * q);       \
      xr[4 + q] = *(const float4*)(xrow0 + rstride + (long)(tt)*D_N + 4 * q); \
    }                                                                 \
  }

#define XPREP(bidx)                                                   \
  {                                                                   \
    f16 c0[16], c1[16];                                               \
    _Pragma("unroll") for (int q = 0; q < 4; ++q) {                   \
      const float* f0 = (const float*)&xr[q];                         \
      const float* f1 = (const float*)&xr[4 + q];                     \
      _Pragma("unroll") for (int e = 0; e < 4; ++e) {                 \
        c0[4 * q + e] = (f16)f0[e];                                   \
        c1[4 * q + e] = (f16)f1[e];                                   \
      }                                                               \
    }                                                                 \
    _Pragma("unroll") for (int q = 0; q < 4; ++q) {                   \
      f16x4 v0 = {c0[4 * q], c0[4 * q + 1], c0[4 * q + 2], c0[4 * q + 3]}; \
      f16x4 v1 = {c1[4 * q], c1[4 * q + 1], c1[4 * q + 2], c1[4 * q + 3]}; \
      *(f16x4*)&X16[bidx][2 * p][16 * jbk + 4 * q] = v0;              \
      *(f16x4*)&X16[bidx][2 * p + 1][16 * jbk + 4 * q] = v1;          \
    }                                                                 \
    _Pragma("unroll") for (int c = 0; c < 16; ++c) {                  \
      *(u32*)&Xt16[bidx][16 * jbk + c][2 * p] = pk2(c0[c], c1[c]);    \
    }                                                                 \
  }

  // prologue: IO stages x(0) into buf0 and preloads x(1); P-waves tgt(0)+prio
  if (wid >= 4) {
    XLOAD(0);
    XPREP(0);
    XLOAD(1);
  } else {
    __builtin_amdgcn_s_setprio(1);
    tcur = tg[(long)lane * T_N];
  }
  __syncthreads();

  for (int t = 0; t < T_N; ++t) {
    const int pbn = (pb == 2) ? 0 : pb + 1;  // (t+1) % 3
    const int sp = t & 1;                    // pairs parity
    f32x16 acc1[2];  // Px: live across the barrier into phase F

    // ================= phase 1 =================
    if (wid < 4) {
      // tgt prefetch for t+1 (used next step; latency fully covered)
      if (t + 1 < T_N) tnxt = tg[(long)lane * T_N + (t + 1)];

      // ---- hoisted row pointers (one add each; reads use imm offsets)
      const f16* rA0 = &X16[pb][l31][8 * h];
      const f16* rA1 = &X16[pb][32 + l31][8 * h];
      const f16* rQ0 = &X16[pb][l31][32 * w + 4 * h];
      const f16* rQ1 = &X16[pb][32 + l31][32 * w + 4 * h];
      const float* rT = &theta[32 * w + 4 * h];

      // ---- ar first half (ks 0-3), issued before pack so LDS service
      // overlaps pack's VALU (burst-smoothing across the 4 P-waves)
      f16x4 ar[8][4];
#pragma unroll
      for (int ks = 0; ks < 4; ++ks) {
        ar[ks][0] = *(const f16x4*)(rA0 + 16 * ks);
        ar[ks][1] = *(const f16x4*)(rA0 + 16 * ks + 4);
        ar[ks][2] = *(const f16x4*)(rA1 + 16 * ks);
        ar[ks][3] = *(const f16x4*)(rA1 + 16 * ks + 4);
      }

      // ---- (B) pack Pt into f16 pair quads (hi only)
      u32 pqh[4][4][2];
#pragma unroll
      for (int jm = 0; jm < 4; ++jm)
#pragma unroll
        for (int rq = 0; rq < 4; ++rq) {
          pqh[jm][rq][0] = pkrtz(Pacc[jm][4 * rq + 0], Pacc[jm][4 * rq + 1]);
          pqh[jm][rq][1] = pkrtz(Pacc[jm][4 * rq + 2], Pacc[jm][4 * rq + 3]);
        }

      // ---- ar second half + D-phase xq/tq (needed only late, in D)
#pragma unroll
      for (int ks = 4; ks < 8; ++ks) {
        ar[ks][0] = *(const f16x4*)(rA0 + 16 * ks);
        ar[ks][1] = *(const f16x4*)(rA0 + 16 * ks + 4);
        ar[ks][2] = *(const f16x4*)(rA1 + 16 * ks);
        ar[ks][3] = *(const f16x4*)(rA1 + 16 * ks + 4);
      }
      f16x4 xq[2][4];
      float4 tq[4];
#pragma unroll
      for (int rq = 0; rq < 4; ++rq) {
        tq[rq] = *(const float4*)(rT + 8 * rq);
        xq[0][rq] = *(const f16x4*)(rQ0 + 8 * rq);
        xq[1][rq] = *(const f16x4*)(rQ1 + 8 * rq);
      }

      // ---- (C) m1: acc1 = X*Pt^T  and  m1': accT = Pt*X^T (for q,y reduction)
      f32x16 accT[2];
#pragma unroll
      for (int ks = 0; ks < 8; ++ks) {
        const int a = ks >> 1, s = 2 * (ks & 1);
        f16x8 bh = bfrag(h, pqh[a][s][0], pqh[a][s][1], pqh[a][s + 1][0], pqh[a][s + 1][1]);
        f16x8 a0 = cat8(ar[ks][0], ar[ks][1]);
        f16x8 a1 = cat8(ar[ks][2], ar[ks][3]);
        if (ks == 0) {
          acc1[0] = __builtin_amdgcn_mfma_f32_32x32x16_f16(a0, bh, Z, 0, 0, 0);
          acc1[1] = __builtin_amdgcn_mfma_f32_32x32x16_f16(a1, bh, Z, 0, 0, 0);
          accT[0] = __builtin_amdgcn_mfma_f32_32x32x16_f16(bh, a0, Z, 0, 0, 0);
          accT[1] = __builtin_amdgcn_mfma_f32_32x32x16_f16(bh, a1, Z, 0, 0, 0);
        } else {
          acc1[0] = __builtin_amdgcn_mfma_f32_32x32x16_f16(a0, bh, acc1[0], 0, 0, 0);
          acc1[1] = __builtin_amdgcn_mfma_f32_32x32x16_f16(a1, bh, acc1[1], 0, 0, 0);
          accT[0] = __builtin_amdgcn_mfma_f32_32x32x16_f16(bh, a0, accT[0], 0, 0, 0);
          accT[1] = __builtin_amdgcn_mfma_f32_32x32x16_f16(bh, a1, accT[1], 0, 0, 0);
        }
      }

      // ---- (D) q = x'Ptx, y = x'theta per b: in-lane over regs (i), one
      // permlane half-sum, one LDS write per (wave,b).
#pragma unroll
      for (int bt = 0; bt < 2; ++bt) {
        float q = 0.0f, y = 0.0f;
#pragma unroll
        for (int rq = 0; rq < 4; ++rq) {
          const float* tqf = (const float*)&tq[rq];
#pragma unroll
          for (int c = 0; c < 4; ++c) {
            const float xf = (float)xq[bt][rq][c];
            q = fmaf(xf, accT[bt][4 * rq + c], q);
            y = fmaf(xf, tqf[c], y);
          }
        }
        q = hsum32(q);
        y = hsum32(y);
        if (h == 0) {
          float2 v; v.x = q; v.y = y;
          *(float2*)&pairs[sp][w][32 * bt + l31][0] = v;
        }
      }
    } else {
      // IO: stage x(t+1) into buf (t+1)%3 (vmcnt wait ~0: loaded a full step
      // ago), then issue the x(t+2) loads (stay in flight across the barrier)
      if (t + 1 < T_N) XPREP(pbn);
      if (t + 2 < T_N) XLOAD(t + 2);
    }
    wg_barrier();

    // ================= phase 2 =================
    if (wid < 4) {
      // ---- (1) pairs reads FIRST (in-order LDS return: E' starts earliest)
      float2 pv[4];
#pragma unroll
      for (int ww = 0; ww < 4; ++ww)
        pv[ww] = *(const float2*)&pairs[sp][ww][lane][0];

      // ---- (2) E': per-lane b=lane; fold negsc into rd -> rdm
      {
        const float qs = pv[0].x + pv[1].x + pv[2].x + pv[3].x;
        const float ys = pv[0].y + pv[1].y + pv[2].y + pv[3].y;
        const float rd = __builtin_amdgcn_rcpf(qs + FEPS * ft);  // 1e-7 rel
        const float rdm = rd * (-ft * INVB);                     // rd * negsc
        float2 v2; v2.x = rdm; v2.y = tcur - ys;
        *(float2*)&rw[w][lane][0] = v2;
      }

      // ---- (3) hoisted rw gather (16 float4) BEFORE any xt reads, so F's
      // operands are not queued behind 32 xt returns (in-order LDS pipe)
      float4 rwq[2][4][2];
#pragma unroll
      for (int bm = 0; bm < 2; ++bm)
#pragma unroll
        for (int rq = 0; rq < 4; ++rq) {
          const int b0 = 32 * bm + 8 * rq + 4 * h;
          rwq[bm][rq][0] = *(const float4*)&rw[w][b0][0];
          rwq[bm][rq][1] = *(const float4*)&rw[w][b0 + 2][0];
        }
      __builtin_amdgcn_sched_barrier(0);  // pin: rw gather issues before xt

      // ---- (4) xt reads for G ks=0,1 (ks=2,3 issued inside G)
      const f16* rXt[4];
#pragma unroll
      for (int jm = 0; jm < 4; ++jm) rXt[jm] = &Xt16[pb][32 * jm + l31][8 * h];
      f16x4 xt01[2][4][2];
#pragma unroll
      for (int ks = 0; ks < 2; ++ks)
#pragma unroll
        for (int jm = 0; jm < 4; ++jm) {
          xt01[ks][jm][0] = *(const f16x4*)(rXt[jm] + 16 * ks);
          xt01[ks][jm][1] = *(const f16x4*)(rXt[jm] + 16 * ks + 4);
        }

      // ---- (F) km = acc1*rdm (pre-folded), tsum over km*err, pack kq
      u32 kq[2][4][2];
      float tsum = 0.0f;
#pragma unroll
      for (int bm = 0; bm < 2; ++bm)
#pragma unroll
        for (int rq = 0; rq < 4; ++rq) {
          const float4 qa = rwq[bm][rq][0];  // rdm0,e0,rdm1,e1
          const float4 qb = rwq[bm][rq][1];  // rdm2,e2,rdm3,e3
          const float km0 = acc1[bm][4 * rq + 0] * qa.x;
          const float km1 = acc1[bm][4 * rq + 1] * qa.z;
          const float km2 = acc1[bm][4 * rq + 2] * qb.x;
          const float km3 = acc1[bm][4 * rq + 3] * qb.z;
          tsum += km0 * qa.y + km1 * qa.w + km2 * qb.y + km3 * qb.w;
          kq[bm][rq][0] = pkrtz(km0, km1);
          kq[bm][rq][1] = pkrtz(km2, km3);
        }
      tsum = hsum32(tsum);
      // theta delta = mean_b(K err) = tsum * (-1/ft)  (km = -ft/64 * K)
      const float negftinv = -__builtin_amdgcn_rcpf(ft);
      if (h == 0) theta[i32] = fmaf(tsum, negftinv, theta[i32]);

      // ---- (G) m2: Pt += Xt * km, rolling xt reads for ks=2,3
      f16x4 xt2[4][2], xt3[4][2];
#pragma unroll
      for (int jm = 0; jm < 4; ++jm) {
        xt2[jm][0] = *(const f16x4*)(rXt[jm] + 32);
        xt2[jm][1] = *(const f16x4*)(rXt[jm] + 36);
      }
      {  // ks = 0
        f16x8 bh = bfrag(h, kq[0][0][0], kq[0][0][1], kq[0][1][0], kq[0][1][1]);
#pragma unroll
        for (int jm = 0; jm < 4; ++jm)
          Pacc[jm] = __builtin_amdgcn_mfma_f32_32x32x16_f16(
              cat8(xt01[0][jm][0], xt01[0][jm][1]), bh, Pacc[jm], 0, 0, 0);
      }
#pragma unroll
      for (int jm = 0; jm < 4; ++jm) {
        xt3[jm][0] = *(const f16x4*)(rXt[jm] + 48);
        xt3[jm][1] = *(const f16x4*)(rXt[jm] + 52);
      }
      {  // ks = 1
        f16x8 bh = bfrag(h, kq[0][2][0], kq[0][2][1], kq[0][3][0], kq[0][3][1]);
#pragma unroll
        for (int jm = 0; jm < 4; ++jm)
          Pacc[jm] = __builtin_amdgcn_mfma_f32_32x32x16_f16(
              cat8(xt01[1][jm][0], xt01[1][jm][1]), bh, Pacc[jm], 0, 0, 0);
      }
      {  // ks = 2
        f16x8 bh = bfrag(h, kq[1][0][0], kq[1][0][1], kq[1][1][0], kq[1][1][1]);
#pragma unroll
        for (int jm = 0; jm < 4; ++jm)
          Pacc[jm] = __builtin_amdgcn_mfma_f32_32x32x16_f16(
              cat8(xt2[jm][0], xt2[jm][1]), bh, Pacc[jm], 0, 0, 0);
      }
      {  // ks = 3
        f16x8 bh = bfrag(h, kq[1][2][0], kq[1][2][1], kq[1][3][0], kq[1][3][1]);
#pragma unroll
        for (int jm = 0; jm < 4; ++jm)
          Pacc[jm] = __builtin_amdgcn_mfma_f32_32x32x16_f16(
              cat8(xt3[jm][0], xt3[jm][1]), bh, Pacc[jm], 0, 0, 0);
      }
      tcur = tnxt;
    } else if (wid == 4) {
      // IO wave 4: redundant ys-sum, store raw attention (overlapped with F/G)
      float ys = 0.0f;
#pragma unroll
      for (int ww = 0; ww < 4; ++ww) ys += pairs[sp][ww][lane][1];
      attn[(long)lane * T_N + t] = ys;
    }
    // NO end-of-step barrier (R11 race audit: triple-buffered X, parity pairs)

    pb = pbn;
    ft *= FF;
  }
#undef XLOAD
#undef XPREP
}

// softmax over time per batch row (in place on raw attn)
__global__ void softmax_k(float* __restrict__ attn) {
  const int b = blockIdx.x;
  float* row = attn + (long)b * T_N;
  __shared__ float sv[T_N];
  __shared__ float red[256];
  const int tid = threadIdx.x;
  float m = -1e30f;
  for (int k = tid; k < T_N; k += 256) {
    const float v = row[k];
    sv[k] = v;
    m = fmaxf(m, v);
  }
  red[tid] = m;
  __syncthreads();
  for (int off = 128; off > 0; off >>= 1) {
    if (tid < off) red[tid] = fmaxf(red[tid], red[tid + off]);
    __syncthreads();
  }
  const float M = red[0];
  __syncthreads();
  float s = 0.0f;
  for (int k = tid; k < T_N; k += 256) {
    const float e = __expf(sv[k] - M);
    sv[k] = e;
    s += e;
  }
  red[tid] = s;
  __syncthreads();
  for (int off = 128; off > 0; off >>= 1) {
    if (tid < off) red[tid] += red[tid + off];
    __syncthreads();
  }
  const float inv = 1.0f / red[0];
  for (int k = tid; k < T_N; k += 256) row[k] = sv[k] * inv;
}

// out[b][d] = sum_t x[b][t][d] * attn_norm[b][t]
__global__ void einsum_k(const float* __restrict__ xg,
                         const float* __restrict__ attn,
                         float* __restrict__ out) {
  const int b = blockIdx.x;
  const int d = threadIdx.x;  // 128 threads
  __shared__ float as[T_N];
  for (int k = d; k < T_N; k += 128) as[k] = attn[(long)b * T_N + k];
  __syncthreads();
  const float* xb = xg + (long)b * T_N * D_N + d;
  float acc = 0.0f;
#pragma unroll 4
  for (int t = 0; t < T_N; ++t) acc += xb[(long)t * D_N] * as[t];
  out[b * D_N + d] = acc;
}

extern "C" void kernel_launch(void* const* d_in, const int* in_sizes, int n_in,
                              void* d_out, int out_size, void* d_ws, size_t ws_size,
                              hipStream_t stream) {
  const float* x = (const float*)d_in[0];
  const float* tgt = (const float*)d_in[1];
  float* out = (float*)d_out;
  float* attn = out + B_N * D_N;  // outputs: [output (B,D) | attn_norm (B,T)]

  rls_seq<<<dim3(1), dim3(512), 0, stream>>>(x, tgt, attn);
  softmax_k<<<dim3(B_N), dim3(256), 0, stream>>>(attn);
  einsum_k<<<dim3(B_N), dim3(128), 0, stream>>>(x, attn, out);
}